// Round 2
// baseline (331.620 us; speedup 1.0000x reference)
//
#include <hip/hip_runtime.h>
#include <hip/hip_bf16.h>
#include <stdint.h>

// Problem constants (AudioEncoder_14800457302115)
#define B_SZ   4
#define T_LEN  480000
#define S_LEN  240000        // conv output length: (480000 + 2*2 - 5)/2 + 1
#define EMB    64
#define PDIM   64
#define KS     5
#define SBLK   64            // s positions per block (4 waves x 16)
#define NBLK_S (S_LEN / SBLK)  // 3750

typedef __attribute__((ext_vector_type(8))) __bf16  bf16x8;
typedef __attribute__((ext_vector_type(4))) float   f32x4;

__global__ __launch_bounds__(256) void audio_enc_kernel(
    const float* __restrict__ audio,   // (B, T) f32
    const float* __restrict__ conv_w,  // (64, 1, 5)
    const float* __restrict__ conv_b,  // (64,)
    const float* __restrict__ lin_w,   // (64, 64) p-major
    const float* __restrict__ lin_b,   // (64,)
    float* __restrict__ out)           // (B, S, 64) f32
{
  __shared__ __align__(16) float xs[2 * SBLK + 4];   // 131 used: x[2*s0-2 .. 2*s0+128]
  __shared__ __align__(16) float cw[EMB * KS];       // conv weights
  __shared__ __align__(16) float cb[EMB];
  __shared__ __align__(16) float lb[PDIM];
  __shared__ __align__(16) float ot[4][16][68];      // per-wave out tile, 272B row stride

  const int tid  = threadIdx.x;
  const int bidx = blockIdx.x;
  const int b    = bidx / NBLK_S;
  const int s0   = (bidx % NBLK_S) * SBLK;

  // ---- stage x window, conv weights, biases into LDS ----
  if (tid < 2 * SBLK + 3) {                 // 131 samples
    int gi = 2 * s0 - 2 + tid;
    float v = 0.f;
    if (gi >= 0 && gi < T_LEN) v = audio[(long)b * T_LEN + gi];
    xs[tid] = v;
  }
  for (int i = tid; i < EMB * KS; i += 256) cw[i] = conv_w[i];
  if (tid < EMB) cb[tid] = conv_b[tid];
  if (tid >= 128 && tid < 128 + PDIM) lb[tid - 128] = lin_b[tid - 128];
  __syncthreads();

  const int w    = tid >> 6;      // wave 0..3
  const int lane = tid & 63;
  const int m    = lane & 15;     // A row index (s) / B col index (p)
  const int q    = lane >> 4;     // quad 0..3
  const int sloc = w * 16 + m;    // s within block for A-operand row

  // ---- conv: this lane's feats directly in A-fragment layout ----
  // A[m = lane&15][k = q*8 + j]; k = channel e; two K-tiles (e 0..31, 32..63)
  const float x0 = xs[2 * sloc + 0];
  const float x1 = xs[2 * sloc + 1];
  const float x2 = xs[2 * sloc + 2];
  const float x3 = xs[2 * sloc + 3];
  const float x4 = xs[2 * sloc + 4];

  bf16x8 afrag[2];
#pragma unroll
  for (int h = 0; h < 2; ++h) {
#pragma unroll
    for (int j = 0; j < 8; ++j) {
      const int e = h * 32 + q * 8 + j;
      const float* wp = &cw[e * KS];
      float a = cb[e];
      a = fmaf(wp[0], x0, a);
      a = fmaf(wp[1], x1, a);
      a = fmaf(wp[2], x2, a);
      a = fmaf(wp[3], x3, a);
      a = fmaf(wp[4], x4, a);
      a = fmaxf(a, 0.f);
      afrag[h][j] = (__bf16)a;
    }
  }

  // ---- B fragments from lin_w: B[k=e][n=p] = lin_w[p][e] ----
  // lane holds col n = lane&15 (+16*nt), rows k = q*8+j
  bf16x8 bfrag[2][4];
#pragma unroll
  for (int nt = 0; nt < 4; ++nt) {
    const int p = nt * 16 + m;
#pragma unroll
    for (int kt = 0; kt < 2; ++kt) {
      const float* src = lin_w + p * 64 + kt * 32 + q * 8;
#pragma unroll
      for (int j = 0; j < 8; ++j) bfrag[kt][nt][j] = (__bf16)src[j];
    }
  }

  // ---- MFMA: 16(s) x 64(p) per wave, K=64 in 2 steps ----
  // C/D: col(p within tile)=lane&15, row(s within tile)=q*4+r   [m89]
#pragma unroll
  for (int nt = 0; nt < 4; ++nt) {
    f32x4 acc = {0.f, 0.f, 0.f, 0.f};
    acc = __builtin_amdgcn_mfma_f32_16x16x32_bf16(afrag[0], bfrag[0][nt], acc, 0, 0, 0);
    acc = __builtin_amdgcn_mfma_f32_16x16x32_bf16(afrag[1], bfrag[1][nt], acc, 0, 0, 0);
    const int p = nt * 16 + m;
    const float bias = lb[p];
#pragma unroll
    for (int r = 0; r < 4; ++r) {
      ot[w][q * 4 + r][p] = acc[r] + bias;   // 2-way bank alias only (free)
    }
  }
  __syncthreads();

  // ---- coalesced store: wave's 16x64 f32 tile = 4KB contiguous in out ----
  const size_t obase = ((size_t)b * S_LEN + (size_t)(s0 + w * 16)) * 64;
#pragma unroll
  for (int it = 0; it < 4; ++it) {
    const int row = it * 4 + (lane >> 4);
    const int col = (lane & 15) * 4;
    float4 v = *reinterpret_cast<const float4*>(&ot[w][row][col]);
    *reinterpret_cast<float4*>(out + obase + (size_t)row * 64 + col) = v;
  }
}

extern "C" void kernel_launch(void* const* d_in, const int* in_sizes, int n_in,
                              void* d_out, int out_size, void* d_ws, size_t ws_size,
                              hipStream_t stream) {
  const float* audio  = (const float*)d_in[0];
  const float* conv_w = (const float*)d_in[1];
  const float* conv_b = (const float*)d_in[2];
  const float* lin_w  = (const float*)d_in[3];
  const float* lin_b  = (const float*)d_in[4];
  float* out = (float*)d_out;

  dim3 grid(B_SZ * NBLK_S);   // 15000 blocks
  dim3 block(256);
  audio_enc_kernel<<<grid, block, 0, stream>>>(audio, conv_w, conv_b, lin_w, lin_b, out);
}

// Round 3
// 275.408 us; speedup vs baseline: 1.2041x; 1.2041x over previous
//
#include <hip/hip_runtime.h>
#include <hip/hip_bf16.h>
#include <stdint.h>

// Problem constants (AudioEncoder_14800457302115)
#define B_SZ    4
#define T_LEN   480000
#define S_LEN   240000          // (480000 + 2*2 - 5)/2 + 1
#define KS      5
#define TPB     15000           // 16-s tiles per batch (240000/16)
#define NTILES  (B_SZ * TPB)    // 60000 wave-tiles
#define GRID    512             // 512 blocks * 4 waves = 2048 waves (2 blk/CU resident)

typedef __attribute__((ext_vector_type(8))) __bf16  bf16x8;
typedef __attribute__((ext_vector_type(4))) float   f32x4;

__global__ __launch_bounds__(256) void audio_enc_kernel(
    const float* __restrict__ audio,   // (B, T)
    const float* __restrict__ conv_w,  // (64, 1, 5)
    const float* __restrict__ conv_b,  // (64,)
    const float* __restrict__ lin_w,   // (64, 64) [p][e]
    const float* __restrict__ lin_b,   // (64,)
    float* __restrict__ out)           // (B, S, 64)
{
  const int lane = threadIdx.x & 63;
  const int m    = lane & 15;          // A row (s) / B col (p)
  const int q    = lane >> 4;          // quad
  const int wv   = (blockIdx.x << 2) | (threadIdx.x >> 6);
  const int nw   = gridDim.x << 2;

  // ---- one-time, tile-invariant register state ----
  // conv weights for this lane's 16 channels e = h*32 + q*8 + j
  float cw[2][8][KS], cbv[2][8];
#pragma unroll
  for (int h = 0; h < 2; ++h)
#pragma unroll
    for (int j = 0; j < 8; ++j) {
      const int e = h * 32 + q * 8 + j;
#pragma unroll
      for (int t = 0; t < KS; ++t) cw[h][j][t] = conv_w[e * KS + t];
      cbv[h][j] = conv_b[e];
    }

  // B fragments: B[k=e][n=p] = lin_w[p][e]; lane: n = m (+16*nt), k = q*8+j
  bf16x8 bfrag[2][4];
#pragma unroll
  for (int nt = 0; nt < 4; ++nt) {
    const int p = nt * 16 + m;
#pragma unroll
    for (int kt = 0; kt < 2; ++kt) {
      const float* src = lin_w + p * 64 + kt * 32 + q * 8;
#pragma unroll
      for (int j = 0; j < 8; ++j) bfrag[kt][nt][j] = (__bf16)src[j];
    }
  }
  float lbv[4];
#pragma unroll
  for (int nt = 0; nt < 4; ++nt) lbv[nt] = lin_b[nt * 16 + m];

  int t = wv;
  if (t >= NTILES) return;

  // ---- per-tile audio window loader (branchless edge clamp) ----
  auto load_tile = [&](int tt, float2& A, float2& B, float& C) {
    const unsigned ut = (unsigned)tt;
    const unsigned b  = ut / TPB;                 // magic-mul divide
    const int s0      = (int)(ut - b * TPB) * 16;
    const int sl      = s0 + m;
    const float* base = audio + (size_t)b * T_LEN;
    const int gi = 2 * sl - 2;                    // window start (pad=2)
    A = *reinterpret_cast<const float2*>(base + (gi < 0 ? 0 : gi));
    if (gi < 0) { A.x = 0.f; A.y = 0.f; }         // only s0==0, m==0
    B = *reinterpret_cast<const float2*>(base + 2 * sl);
    const int ci = 2 * sl + 2;
    float cv = base[ci < T_LEN ? ci : T_LEN - 1];
    C = (ci < T_LEN) ? cv : 0.f;                  // only sl==239999
  };

  float2 fa, fb; float c1;
  load_tile(t, fa, fb, c1);

  while (true) {
    // consume current tile's window into locals, then issue next tile's loads
    const float x0 = fa.x, x1 = fa.y, x2 = fb.x, x3 = fb.y, x4 = c1;
    const unsigned ut = (unsigned)t;
    const unsigned b  = ut / TPB;
    const int s0      = (int)(ut - b * TPB) * 16;

    const int tn = t + nw;
    const bool more = (tn < NTILES);
    if (more) load_tile(tn, fa, fb, c1);          // in-flight during compute

    // ---- conv -> A fragments (A[m][k=q*8+j], k = channel) ----
    bf16x8 af[2];
#pragma unroll
    for (int h = 0; h < 2; ++h)
#pragma unroll
      for (int j = 0; j < 8; ++j) {
        float a = cbv[h][j];
        a = fmaf(cw[h][j][0], x0, a);
        a = fmaf(cw[h][j][1], x1, a);
        a = fmaf(cw[h][j][2], x2, a);
        a = fmaf(cw[h][j][3], x3, a);
        a = fmaf(cw[h][j][4], x4, a);
        a = fmaxf(a, 0.f);
        af[h][j] = (__bf16)a;
      }

    // ---- MFMA 16(s) x 64(p), K=64 in 2 steps; direct C-layout stores ----
    // C/D: col(p)=lane&15, row(s)=q*4+r  [m89]
    float* ob = out + ((size_t)b * S_LEN + (size_t)s0) * 64;
#pragma unroll
    for (int nt = 0; nt < 4; ++nt) {
      f32x4 acc = {0.f, 0.f, 0.f, 0.f};
      acc = __builtin_amdgcn_mfma_f32_16x16x32_bf16(af[0], bfrag[0][nt], acc, 0, 0, 0);
      acc = __builtin_amdgcn_mfma_f32_16x16x32_bf16(af[1], bfrag[1][nt], acc, 0, 0, 0);
      const float bias = lbv[nt];
#pragma unroll
      for (int r = 0; r < 4; ++r) {
        ob[(q * 4 + r) * 64 + nt * 16 + m] = acc[r] + bias;
      }
    }

    if (!more) break;
    t = tn;
  }
}

extern "C" void kernel_launch(void* const* d_in, const int* in_sizes, int n_in,
                              void* d_out, int out_size, void* d_ws, size_t ws_size,
                              hipStream_t stream) {
  const float* audio  = (const float*)d_in[0];
  const float* conv_w = (const float*)d_in[1];
  const float* conv_b = (const float*)d_in[2];
  const float* lin_w  = (const float*)d_in[3];
  const float* lin_b  = (const float*)d_in[4];
  float* out = (float*)d_out;

  audio_enc_kernel<<<dim3(GRID), dim3(256), 0, stream>>>(
      audio, conv_w, conv_b, lin_w, lin_b, out);
}